// Round 10
// baseline (371.818 us; speedup 1.0000x reference)
//
#include <hip/hip_runtime.h>
#include <hip/hip_bf16.h>

#define BN_EPS 1e-5f
#define BINSH 9
#define MAXNB 200
#define NBLK 256

typedef __attribute__((ext_vector_type(8))) short bf16x8v;
typedef __attribute__((ext_vector_type(4))) float f32x4v;

__device__ __forceinline__ float u2f(unsigned x) { return __uint_as_float(x); }
__device__ __forceinline__ unsigned short f2bf(float f) {
    union { __hip_bfloat16 h; unsigned short u; } cv;
    cv.h = __float2bfloat16(f);
    return cv.u;
}

__device__ __forceinline__ int edge_at(const void* p, long long i, int is64) {
    return is64 ? (int)((const long long*)p)[i] : ((const int*)p)[i];
}

__device__ __forceinline__ int detect_is64(const void* eidx, int* sflag, int t) {
    if (t == 0) {
        const int* e32 = (const int*)eidx;
        int nz = 0;
        for (int i = 0; i < 64; ++i) nz += (e32[2 * i + 1] != 0);
        *sflag = (nz == 0) ? 1 : 0;
    }
    return 0;
}

// ---------------- pass A: per-block bin histogram (transposed out) ----------------
__global__ __launch_bounds__(256) void histA_kernel(const void* __restrict__ eidx,
                                                    int* __restrict__ hist2dT,
                                                    int* __restrict__ binhist,
                                                    int E, int NB, int per_block) {
    __shared__ int lh[MAXNB];
    __shared__ int sflag;
    const int t = threadIdx.x;
    detect_is64(eidx, &sflag, t);
    for (int i = t; i < NB; i += 256) lh[i] = 0;
    __syncthreads();
    const int is64 = sflag;
    long long base = (long long)blockIdx.x * per_block;
    long long lim  = base + per_block;
    if (lim > E) lim = E;
    for (long long e = base + t; e < lim; e += 256) {
        int d = edge_at(eidx, (long long)E + e, is64);
        atomicAdd(&lh[d >> BINSH], 1);
    }
    __syncthreads();
    for (int i = t; i < NB; i += 256) {
        hist2dT[i * NBLK + blockIdx.x] = lh[i];
        atomicAdd(&binhist[i], lh[i]);
    }
}

// ---------------- bin-level scan: binrp ----------------
__global__ void binscan_kernel(const int* __restrict__ binhist, int* __restrict__ binrp, int NB) {
    __shared__ int s[256];
    const int t = threadIdx.x;
    int v = (t < NB) ? binhist[t] : 0;
    s[t] = v;
    __syncthreads();
    for (int off = 1; off < 256; off <<= 1) {
        int x = (t >= off) ? s[t - off] : 0;
        __syncthreads();
        s[t] += x;
        __syncthreads();
    }
    if (t < NB) binrp[t] = s[t] - v;
    if (t == 0) binrp[NB] = s[255];
}

// ---------------- per-bin column scan (parallel, coalesced) ----------------
__global__ __launch_bounds__(256) void colscan_kernel(int* __restrict__ hist2dT,
                                                      const int* __restrict__ binrp) {
    __shared__ int s[256];
    const int b = blockIdx.x;
    const int t = threadIdx.x;
    int v = hist2dT[b * NBLK + t];
    s[t] = v;
    __syncthreads();
    for (int off = 1; off < 256; off <<= 1) {
        int x = (t >= off) ? s[t - off] : 0;
        __syncthreads();
        s[t] += x;
        __syncthreads();
    }
    hist2dT[b * NBLK + t] = binrp[b] + s[t] - v;
}

// ---------------- pass B: edge-parallel scatter into reserved ranges ----------------
__global__ __launch_bounds__(256) void passB_kernel(const void* __restrict__ eidx,
                                                    const int* __restrict__ hist2dT,
                                                    int2* __restrict__ ibuf,
                                                    int E, int NB, int per_block) {
    __shared__ int lbase[MAXNB];
    __shared__ int lcur[MAXNB];
    __shared__ int sflag;
    const int t = threadIdx.x;
    detect_is64(eidx, &sflag, t);
    for (int i = t; i < NB; i += 256) {
        lbase[i] = hist2dT[i * NBLK + blockIdx.x];
        lcur[i]  = 0;
    }
    __syncthreads();
    const int is64 = sflag;
    long long base = (long long)blockIdx.x * per_block;
    long long lim  = base + per_block;
    if (lim > E) lim = E;
    for (long long e = base + t; e < lim; e += 256) {
        int sN = edge_at(eidx, e, is64);
        int d  = edge_at(eidx, (long long)E + e, is64);
        int b  = d >> BINSH;
        int pos = lbase[b] + atomicAdd(&lcur[b], 1);
        ibuf[pos] = make_int2(sN, d);
    }
}

// ---------------- per-bin exact sort; computes rp + dis; ep = src only ----------------
__global__ __launch_bounds__(256) void binsort2_kernel(const int2* __restrict__ ibuf,
                                                       const int* __restrict__ binrp,
                                                       int* __restrict__ rp,
                                                       float* __restrict__ dis,
                                                       int* __restrict__ ep, int N) {
    const int b  = blockIdx.x;
    const int d0 = b << BINSH;
    const int dc = min(1 << BINSH, N - d0);
    __shared__ int lcnt[1 << BINSH];
    __shared__ int lofs[1 << BINSH];
    __shared__ int s2[256];
    const int t = threadIdx.x;
    lcnt[t] = 0; lcnt[t + 256] = 0;
    __syncthreads();
    const int ib0 = binrp[b], ib1 = binrp[b + 1];
    const int nE  = ib1 - ib0;
    for (int i = t; i < nE; i += 256) {
        int2 sd = ibuf[ib0 + i];
        atomicAdd(&lcnt[sd.y - d0], 1);
    }
    __syncthreads();
    const int c0 = lcnt[2 * t], c1 = lcnt[2 * t + 1];
    const int pair = c0 + c1;
    s2[t] = pair;
    __syncthreads();
    for (int off = 1; off < 256; off <<= 1) {
        int x = (t >= off) ? s2[t - off] : 0;
        __syncthreads();
        s2[t] += x;
        __syncthreads();
    }
    const int pexcl = s2[t] - pair;
    if (2 * t < dc) {
        rp[d0 + 2 * t + 1] = ib0 + pexcl + c0;
        dis[d0 + 2 * t]    = rsqrtf((float)c0 + 1.0f);
    }
    if (2 * t + 1 < dc) {
        rp[d0 + 2 * t + 2] = ib0 + pexcl + pair;
        dis[d0 + 2 * t + 1] = rsqrtf((float)c1 + 1.0f);
    }
    if (b == 0 && t == 0) rp[0] = 0;
    lofs[2 * t]     = pexcl;
    lofs[2 * t + 1] = pexcl + c0;
    __syncthreads();
    for (int i = t; i < nE; i += 256) {
        int2 sd = ibuf[ib0 + i];
        int dl  = sd.y - d0;
        int pos = ib0 + atomicAdd(&lofs[dl], 1);
        ep[pos] = sd.x;
    }
}

// ---------------- degree-sorted permutation (counting sort, 64 clamped buckets) ----------------
__global__ __launch_bounds__(256) void degA_kernel(const int* __restrict__ rp, int* __restrict__ dblk,
                                                   int* __restrict__ gdeg, int N, int NDB) {
    __shared__ int lh[64];
    const int t = threadIdx.x;
    if (t < 64) lh[t] = 0;
    __syncthreads();
    int n = blockIdx.x * 256 + t;
    if (n < N) {
        int deg = min(rp[n + 1] - rp[n], 63);
        atomicAdd(&lh[deg], 1);
    }
    __syncthreads();
    if (t < 64) {
        dblk[t * NDB + blockIdx.x] = lh[t];
        atomicAdd(&gdeg[t], lh[t]);
    }
}

__global__ void degscan_kernel(const int* __restrict__ gdeg, int* __restrict__ degbase) {
    __shared__ int s[64];
    const int t = threadIdx.x;    // 64 threads
    int v = gdeg[t];
    s[t] = v;
    __syncthreads();
    for (int off = 1; off < 64; off <<= 1) {
        int x = (t >= off) ? s[t - off] : 0;
        __syncthreads();
        s[t] += x;
        __syncthreads();
    }
    degbase[t] = s[t] - v;
}

__global__ __launch_bounds__(512) void degcol_kernel(int* __restrict__ dblk,
                                                     const int* __restrict__ degbase, int NDB) {
    __shared__ int s[512];
    const int d = blockIdx.x;
    const int t = threadIdx.x;
    int v = (t < NDB) ? dblk[d * NDB + t] : 0;
    s[t] = v;
    __syncthreads();
    for (int off = 1; off < 512; off <<= 1) {
        int x = (t >= off) ? s[t - off] : 0;
        __syncthreads();
        s[t] += x;
        __syncthreads();
    }
    if (t < NDB) dblk[d * NDB + t] = degbase[d] + s[t] - v;
}

__global__ __launch_bounds__(256) void degscat_kernel(const int* __restrict__ rp,
                                                      const int* __restrict__ dblk,
                                                      int* __restrict__ perm, int N, int NDB) {
    __shared__ int lcur[64];
    const int t = threadIdx.x;
    if (t < 64) lcur[t] = 0;
    __syncthreads();
    int n = blockIdx.x * 256 + t;
    if (n < N) {
        int deg = min(rp[n + 1] - rp[n], 63);
        int slot = atomicAdd(&lcur[deg], 1);
        perm[dblk[deg * NDB + blockIdx.x] + slot] = n;
    }
}

// ---------------- all weight transposes in one kernel (Wt[c*128+k]) ----------------
__global__ void prep_wt_all_kernel(const float* __restrict__ W1, const float* __restrict__ W2,
                                   const float* __restrict__ W3,
                                   __hip_bfloat16* __restrict__ wt1,
                                   __hip_bfloat16* __restrict__ wt2,
                                   __hip_bfloat16* __restrict__ wt3) {
    int i = blockIdx.x * 256 + threadIdx.x;
    if (i < 16384) {
        int k = i >> 7, c = i & 127;
        wt1[c * 128 + k] = __float2bfloat16(W1[i]);
    } else if (i < 32768) {
        int j = i - 16384;
        int k = j >> 7, c = j & 127;
        wt2[c * 128 + k] = __float2bfloat16(W2[j]);
    } else if (i < 40960) {
        int j = i - 32768;
        int k = j >> 6, c = j & 63;
        wt3[c * 128 + k] = __float2bfloat16(W3[j]);
    }
}

// ---------------- fragment loaders ----------------
__device__ __forceinline__ void load8(const float* p, float* f) {
    float4 v0 = ((const float4*)p)[0];
    float4 v1 = ((const float4*)p)[1];
    f[0] = v0.x; f[1] = v0.y; f[2] = v0.z; f[3] = v0.w;
    f[4] = v1.x; f[5] = v1.y; f[6] = v1.z; f[7] = v1.w;
}
__device__ __forceinline__ void load8(const __hip_bfloat16* p, float* f) {
    uint4 v = *(const uint4*)p;
    f[0] = u2f(v.x << 16); f[1] = u2f(v.x & 0xffff0000u);
    f[2] = u2f(v.y << 16); f[3] = u2f(v.y & 0xffff0000u);
    f[4] = u2f(v.z << 16); f[5] = u2f(v.z & 0xffff0000u);
    f[6] = u2f(v.w << 16); f[7] = u2f(v.w & 0xffff0000u);
}

// ---------------- MFMA GEMM with fused BN finalize+apply ----------------
template <int DOUT, bool BN, typename TH>
__global__ __launch_bounds__(256) void mfma_gemm_kernel(const TH* __restrict__ H,
                                                        const __hip_bfloat16* __restrict__ Wt,
                                                        const float* __restrict__ stats,
                                                        const float* __restrict__ g,
                                                        const float* __restrict__ be,
                                                        float invN,
                                                        __hip_bfloat16* __restrict__ out, int N) {
    constexpr int NCT = DOUT / 16;
    constexpr int LDW = 136;
    __shared__ __hip_bfloat16 sWt[DOUT * LDW];
    __shared__ float sBN[256];
    const int t = threadIdx.x;
    for (int i = t; i < DOUT * 16; i += 256) {
        int row = i >> 4, seg = i & 15;
        *(uint4*)&sWt[row * LDW + seg * 8] = ((const uint4*)Wt)[i];
    }
    if (BN && t < 128) {
        float mu  = stats[t] * invN;
        float var = stats[128 + t] * invN - mu * mu;
        float sc  = g[t] * rsqrtf(var + BN_EPS);
        sBN[t]       = sc;
        sBN[128 + t] = be[t] - mu * sc;
    }
    __syncthreads();
    const int lane = t & 63, wid = t >> 6;
    const int kq = lane >> 4, mrow = lane & 15;
    const int grow = blockIdx.x * 64 + wid * 16 + mrow;
    const int lrow = min(grow, N - 1);
    bf16x8v afrag[4];
#pragma unroll
    for (int ks = 0; ks < 4; ++ks) {
        const int k0 = ks * 32 + kq * 8;
        float f[8];
        load8(H + (size_t)lrow * 128 + k0, f);
        if (BN) {
            float4 s0 = *(const float4*)&sBN[k0];
            float4 s1 = *(const float4*)&sBN[k0 + 4];
            float4 h0 = *(const float4*)&sBN[128 + k0];
            float4 h1 = *(const float4*)&sBN[128 + k0 + 4];
            f[0] = fmaxf(fmaf(f[0], s0.x, h0.x), 0.f);
            f[1] = fmaxf(fmaf(f[1], s0.y, h0.y), 0.f);
            f[2] = fmaxf(fmaf(f[2], s0.z, h0.z), 0.f);
            f[3] = fmaxf(fmaf(f[3], s0.w, h0.w), 0.f);
            f[4] = fmaxf(fmaf(f[4], s1.x, h1.x), 0.f);
            f[5] = fmaxf(fmaf(f[5], s1.y, h1.y), 0.f);
            f[6] = fmaxf(fmaf(f[6], s1.z, h1.z), 0.f);
            f[7] = fmaxf(fmaf(f[7], s1.w, h1.w), 0.f);
        }
        bf16x8v a;
#pragma unroll
        for (int j = 0; j < 8; ++j) a[j] = (short)f2bf(f[j]);
        afrag[ks] = a;
    }
    f32x4v acc[NCT];
#pragma unroll
    for (int ct = 0; ct < NCT; ++ct) acc[ct] = (f32x4v){0.f, 0.f, 0.f, 0.f};
#pragma unroll
    for (int ct = 0; ct < NCT; ++ct) {
#pragma unroll
        for (int ks = 0; ks < 4; ++ks) {
            bf16x8v b = *(const bf16x8v*)&sWt[(ct * 16 + mrow) * LDW + ks * 32 + kq * 8];
            acc[ct] = __builtin_amdgcn_mfma_f32_16x16x32_bf16(afrag[ks], b, acc[ct], 0, 0, 0);
        }
    }
#pragma unroll
    for (int r = 0; r < 4; ++r) {
        int orow = blockIdx.x * 64 + wid * 16 + kq * 4 + r;
        if (orow < N) {
            __hip_bfloat16* op = out + (size_t)orow * DOUT + mrow;
#pragma unroll
            for (int ct = 0; ct < NCT; ++ct) {
                union { unsigned short u; __hip_bfloat16 h; } cv;
                cv.u = f2bf(acc[ct][r]);
                op[ct * 16] = cv.h;
            }
        }
    }
}

// ---------------- aggregation: degree-sorted rows, 8 cols/thread, factored weights ----------------
// out[n] = dis[n] * ( hw[n]*dis[n] + Σ_e hw[src_e]*dis[src_e] ) + bias
__device__ __forceinline__ void acc8(float* a, uint4 v, float w) {
    a[0] += u2f(v.x << 16) * w;  a[1] += u2f(v.x & 0xffff0000u) * w;
    a[2] += u2f(v.y << 16) * w;  a[3] += u2f(v.y & 0xffff0000u) * w;
    a[4] += u2f(v.z << 16) * w;  a[5] += u2f(v.z & 0xffff0000u) * w;
    a[6] += u2f(v.w << 16) * w;  a[7] += u2f(v.w & 0xffff0000u) * w;
}

template <int D, bool OUTBF>
__global__ __launch_bounds__(256) void agg_kernel(const __hip_bfloat16* __restrict__ hw,
                                                  const int* __restrict__ rp,
                                                  const int* __restrict__ ep,
                                                  const float* __restrict__ dis,
                                                  const int* __restrict__ perm,
                                                  const float* __restrict__ bias,
                                                  void* __restrict__ outv, int N) {
    constexpr int LPR = D / 8;              // lanes per row, 8 cols each
    const int t = threadIdx.x;
    const int gtid = blockIdx.x * 256 + t;
    const int idx  = gtid / LPR;
    const int lane = gtid % LPR;
    if (idx >= N) return;
    const int n = perm[idx];
    const uint4* hw8 = (const uint4*)hw;
    float a[8] = {0.f, 0.f, 0.f, 0.f, 0.f, 0.f, 0.f, 0.f};
    const float dn = dis[n];
    uint4 hv = hw8[(size_t)n * LPR + lane];
    acc8(a, hv, dn);                        // self-loop (×dn later)
    int e0 = rp[n], e1 = rp[n + 1];
    int e = e0;
    for (; e + 4 <= e1; e += 4) {
        int p0 = ep[e + 0];
        int p1 = ep[e + 1];
        int p2 = ep[e + 2];
        int p3 = ep[e + 3];
        uint4 v0 = hw8[(size_t)p0 * LPR + lane];
        uint4 v1 = hw8[(size_t)p1 * LPR + lane];
        uint4 v2 = hw8[(size_t)p2 * LPR + lane];
        uint4 v3 = hw8[(size_t)p3 * LPR + lane];
        acc8(a, v0, dis[p0]);
        acc8(a, v1, dis[p1]);
        acc8(a, v2, dis[p2]);
        acc8(a, v3, dis[p3]);
    }
    for (; e < e1; ++e) {
        int p = ep[e];
        uint4 v = hw8[(size_t)p * LPR + lane];
        acc8(a, v, dis[p]);
    }
    float4 b0 = *(const float4*)(bias + lane * 8);
    float4 b1 = *(const float4*)(bias + lane * 8 + 4);
    a[0] = fmaf(a[0], dn, b0.x); a[1] = fmaf(a[1], dn, b0.y);
    a[2] = fmaf(a[2], dn, b0.z); a[3] = fmaf(a[3], dn, b0.w);
    a[4] = fmaf(a[4], dn, b1.x); a[5] = fmaf(a[5], dn, b1.y);
    a[6] = fmaf(a[6], dn, b1.z); a[7] = fmaf(a[7], dn, b1.w);
    if (OUTBF) {
        uint4 o;
        o.x = (unsigned)f2bf(a[0]) | ((unsigned)f2bf(a[1]) << 16);
        o.y = (unsigned)f2bf(a[2]) | ((unsigned)f2bf(a[3]) << 16);
        o.z = (unsigned)f2bf(a[4]) | ((unsigned)f2bf(a[5]) << 16);
        o.w = (unsigned)f2bf(a[6]) | ((unsigned)f2bf(a[7]) << 16);
        ((uint4*)outv)[(size_t)n * LPR + lane] = o;
    } else {
        float4* op = (float4*)outv + ((size_t)n * D + lane * 8) / 4;
        op[0] = make_float4(a[0], a[1], a[2], a[3]);
        op[1] = make_float4(a[4], a[5], a[6], a[7]);
    }
}

// ---------------- batchnorm stats (bf16 input, raw sums; 256 blocks) ----------------
__global__ void bn_stats_kernel(const __hip_bfloat16* __restrict__ X, float* __restrict__ stats, int N) {
    const int t  = threadIdx.x;
    const int c4 = t & 31;
    const int rg = t >> 5;
    const uint2* X4 = (const uint2*)X;
    float s0=0,s1=0,s2=0,s3=0,q0=0,q1=0,q2=0,q3=0;
    for (int r = blockIdx.x * 8 + rg; r < N; r += gridDim.x * 8) {
        uint2 v = X4[(size_t)r * 32 + c4];
        float f0 = u2f(v.x << 16), f1 = u2f(v.x & 0xffff0000u);
        float f2 = u2f(v.y << 16), f3 = u2f(v.y & 0xffff0000u);
        s0 += f0; q0 += f0 * f0;
        s1 += f1; q1 += f1 * f1;
        s2 += f2; q2 += f2 * f2;
        s3 += f3; q3 += f3 * f3;
    }
    __shared__ float ls[8][32][8];
    ls[rg][c4][0] = s0; ls[rg][c4][1] = s1; ls[rg][c4][2] = s2; ls[rg][c4][3] = s3;
    ls[rg][c4][4] = q0; ls[rg][c4][5] = q1; ls[rg][c4][6] = q2; ls[rg][c4][7] = q3;
    __syncthreads();
    if (t < 32) {
        float a[8] = {0,0,0,0,0,0,0,0};
        for (int g = 0; g < 8; ++g)
            for (int k = 0; k < 8; ++k) a[k] += ls[g][t][k];
        for (int k = 0; k < 4; ++k) {
            atomicAdd(&stats[t * 4 + k], a[k]);
            atomicAdd(&stats[128 + t * 4 + k], a[4 + k]);
        }
    }
}

// ---------------- host launch ----------------
extern "C" void kernel_launch(void* const* d_in, const int* in_sizes, int n_in,
                              void* d_out, int out_size, void* d_ws, size_t ws_size,
                              hipStream_t stream) {
    const float* x   = (const float*)d_in[0];
    const void*  eix = d_in[1];
    const float* W1  = (const float*)d_in[2];
    const float* b1  = (const float*)d_in[3];
    const float* g1  = (const float*)d_in[4];
    const float* be1 = (const float*)d_in[5];
    const float* W2  = (const float*)d_in[6];
    const float* b2  = (const float*)d_in[7];
    const float* g2  = (const float*)d_in[8];
    const float* be2 = (const float*)d_in[9];
    const float* W3  = (const float*)d_in[10];
    const float* b3  = (const float*)d_in[11];
    float* outp = (float*)d_out;

    const int N = in_sizes[0] / 128;
    const int E = in_sizes[1] / 2;
    const int NB = (N + (1 << BINSH) - 1) >> BINSH;
    const int NDB = (N + 255) / 256;

    char* base = (char*)d_ws;
    size_t off = 0;
    auto alloc = [&](size_t bytes) -> char* {
        char* p = base + off;
        off = (off + bytes + 255) & ~(size_t)255;
        return p;
    };
    __hip_bfloat16* A = (__hip_bfloat16*)alloc((size_t)N * 128 * 2);
    __hip_bfloat16* B = (__hip_bfloat16*)alloc((size_t)N * 128 * 2);
    int*   rp      = (int*)alloc((size_t)(N + 1) * 4);
    float* dis     = (float*)alloc((size_t)N * 4);
    int*   ep      = (int*)alloc((size_t)E * 4);
    int2*  ibuf    = (int2*)alloc((size_t)E * 8);
    int*   hist2dT = (int*)alloc((size_t)MAXNB * NBLK * 4);
    int*   binrp   = (int*)alloc((MAXNB + 1) * 4);
    int*   perm    = (int*)alloc((size_t)N * 4);
    int*   dblk    = (int*)alloc((size_t)64 * NDB * 4);
    int*   degbase = (int*)alloc(64 * 4);
    // contiguous zero-region: binhist (pads to 1024) + stats1 (1024) + stats2 (1024) + gdeg (256)
    int*   binhist = (int*)alloc(MAXNB * 4);
    float* stats1  = (float*)alloc(256 * 4);
    float* stats2  = (float*)alloc(256 * 4);
    int*   gdeg    = (int*)alloc(64 * 4);
    __hip_bfloat16* wt1 = (__hip_bfloat16*)alloc(128 * 128 * 2);
    __hip_bfloat16* wt2 = (__hip_bfloat16*)alloc(128 * 128 * 2);
    __hip_bfloat16* wt3 = (__hip_bfloat16*)alloc(64 * 128 * 2);
    (void)ws_size; (void)n_in; (void)out_size;

    const int per_block = (E + NBLK - 1) / NBLK;

    // ---- graph preprocessing ----
    hipMemsetAsync(binhist, 0, 3 * 1024 + 256, stream);   // binhist+stats1+stats2+gdeg
    histA_kernel<<<NBLK, 256, 0, stream>>>(eix, hist2dT, binhist, E, NB, per_block);
    binscan_kernel<<<1, 256, 0, stream>>>(binhist, binrp, NB);
    colscan_kernel<<<NB, 256, 0, stream>>>(hist2dT, binrp);
    passB_kernel<<<NBLK, 256, 0, stream>>>(eix, hist2dT, ibuf, E, NB, per_block);
    binsort2_kernel<<<NB, 256, 0, stream>>>(ibuf, binrp, rp, dis, ep, N);
    // degree-sorted permutation
    degA_kernel<<<NDB, 256, 0, stream>>>(rp, dblk, gdeg, N, NDB);
    degscan_kernel<<<1, 64, 0, stream>>>(gdeg, degbase);
    degcol_kernel<<<64, 512, 0, stream>>>(dblk, degbase, NDB);
    degscat_kernel<<<NDB, 256, 0, stream>>>(rp, dblk, perm, N, NDB);
    prep_wt_all_kernel<<<160, 256, 0, stream>>>(W1, W2, W3, wt1, wt2, wt3);

    const float invN = 1.0f / (float)N;
    const int gemm_grid   = (N + 63) / 64;
    const int agg128_grid = (int)(((long long)N * 16 + 255) / 256);
    const int agg64_grid  = (int)(((long long)N * 8 + 255) / 256);

    // ---- layer 1 ----
    mfma_gemm_kernel<128, false, float><<<gemm_grid, 256, 0, stream>>>(
        x, wt1, nullptr, nullptr, nullptr, 0.f, A, N);
    agg_kernel<128, true><<<agg128_grid, 256, 0, stream>>>(A, rp, ep, dis, perm, b1, B, N);
    bn_stats_kernel<<<256, 256, 0, stream>>>(B, stats1, N);

    // ---- layer 2 (BN finalize fused into gemm) ----
    mfma_gemm_kernel<128, true, __hip_bfloat16><<<gemm_grid, 256, 0, stream>>>(
        B, wt2, stats1, g1, be1, invN, A, N);
    agg_kernel<128, true><<<agg128_grid, 256, 0, stream>>>(A, rp, ep, dis, perm, b2, B, N);
    bn_stats_kernel<<<256, 256, 0, stream>>>(B, stats2, N);

    // ---- layer 3 ----
    mfma_gemm_kernel<64, true, __hip_bfloat16><<<gemm_grid, 256, 0, stream>>>(
        B, wt3, stats2, g2, be2, invN, A, N);
    agg_kernel<64, false><<<agg64_grid, 256, 0, stream>>>(A, rp, ep, dis, perm, b3, outp, N);
}

// Round 11
// 364.983 us; speedup vs baseline: 1.0187x; 1.0187x over previous
//
#include <hip/hip_runtime.h>
#include <hip/hip_bf16.h>

#define BN_EPS 1e-5f
#define BINSH 9
#define MAXNB 200
#define NBLK 256

typedef __attribute__((ext_vector_type(8))) short bf16x8v;
typedef __attribute__((ext_vector_type(4))) float f32x4v;

__device__ __forceinline__ float u2f(unsigned x) { return __uint_as_float(x); }
__device__ __forceinline__ unsigned short f2bf(float f) {
    union { __hip_bfloat16 h; unsigned short u; } cv;
    cv.h = __float2bfloat16(f);
    return cv.u;
}

__device__ __forceinline__ int edge_at(const void* p, long long i, int is64) {
    return is64 ? (int)((const long long*)p)[i] : ((const int*)p)[i];
}

__device__ __forceinline__ void detect_is64(const void* eidx, int* sflag, int t) {
    if (t == 0) {
        const int* e32 = (const int*)eidx;
        int nz = 0;
        for (int i = 0; i < 64; ++i) nz += (e32[2 * i + 1] != 0);
        *sflag = (nz == 0) ? 1 : 0;
    }
}

// ---------------- pass A: per-block bin histogram + (tail blocks) weight transpose ----------------
__global__ __launch_bounds__(256) void histA_kernel(const void* __restrict__ eidx,
                                                    int* __restrict__ hist2dT,
                                                    int* __restrict__ binhist,
                                                    const float* __restrict__ W1,
                                                    const float* __restrict__ W2,
                                                    const float* __restrict__ W3,
                                                    __hip_bfloat16* __restrict__ wt1,
                                                    __hip_bfloat16* __restrict__ wt2,
                                                    __hip_bfloat16* __restrict__ wt3,
                                                    int E, int NB, int per_block) {
    const int t = threadIdx.x;
    if (blockIdx.x >= NBLK) {
        // weight transpose: Wt[c*128+k]
        int i = (blockIdx.x - NBLK) * 256 + t;
        if (i < 16384) {
            int k = i >> 7, c = i & 127;
            wt1[c * 128 + k] = __float2bfloat16(W1[i]);
        } else if (i < 32768) {
            int j = i - 16384, k = j >> 7, c = j & 127;
            wt2[c * 128 + k] = __float2bfloat16(W2[j]);
        } else if (i < 40960) {
            int j = i - 32768, k = j >> 6, c = j & 63;
            wt3[c * 128 + k] = __float2bfloat16(W3[j]);
        }
        return;
    }
    __shared__ int lh[MAXNB];
    __shared__ int sflag;
    detect_is64(eidx, &sflag, t);
    for (int i = t; i < NB; i += 256) lh[i] = 0;
    __syncthreads();
    const int is64 = sflag;
    long long base = (long long)blockIdx.x * per_block;
    long long lim  = base + per_block;
    if (lim > E) lim = E;
    for (long long e = base + t; e < lim; e += 256) {
        int d = edge_at(eidx, (long long)E + e, is64);
        atomicAdd(&lh[d >> BINSH], 1);
    }
    __syncthreads();
    for (int i = t; i < NB; i += 256) {
        hist2dT[i * NBLK + blockIdx.x] = lh[i];
        atomicAdd(&binhist[i], lh[i]);
    }
}

// ---------------- colscan (absorbs binscan): per-bin base + column prefix ----------------
__global__ __launch_bounds__(256) void colscan_kernel(int* __restrict__ hist2dT,
                                                      const int* __restrict__ binhist,
                                                      int* __restrict__ binrp, int NB) {
    __shared__ int s[256];
    __shared__ int sbase;
    const int b = blockIdx.x;
    const int t = threadIdx.x;
    // base = sum(binhist[0..b))
    s[t] = (t < b) ? binhist[t] : 0;
    __syncthreads();
    for (int off = 128; off > 0; off >>= 1) {
        if (t < off) s[t] += s[t + off];
        __syncthreads();
    }
    if (t == 0) sbase = s[0];
    __syncthreads();
    const int base = sbase;
    if (t == 0) {
        binrp[b] = base;
        if (b == NB - 1) binrp[NB] = base + binhist[b];
    }
    // column scan of this bin's per-block counts
    int v = hist2dT[b * NBLK + t];
    s[t] = v;
    __syncthreads();
    for (int off = 1; off < 256; off <<= 1) {
        int x = (t >= off) ? s[t - off] : 0;
        __syncthreads();
        s[t] += x;
        __syncthreads();
    }
    hist2dT[b * NBLK + t] = base + s[t] - v;
}

// ---------------- pass B: edge-parallel scatter into reserved ranges ----------------
__global__ __launch_bounds__(256) void passB_kernel(const void* __restrict__ eidx,
                                                    const int* __restrict__ hist2dT,
                                                    int2* __restrict__ ibuf,
                                                    int E, int NB, int per_block) {
    __shared__ int lbase[MAXNB];
    __shared__ int lcur[MAXNB];
    __shared__ int sflag;
    const int t = threadIdx.x;
    detect_is64(eidx, &sflag, t);
    for (int i = t; i < NB; i += 256) {
        lbase[i] = hist2dT[i * NBLK + blockIdx.x];
        lcur[i]  = 0;
    }
    __syncthreads();
    const int is64 = sflag;
    long long base = (long long)blockIdx.x * per_block;
    long long lim  = base + per_block;
    if (lim > E) lim = E;
    for (long long e = base + t; e < lim; e += 256) {
        int sN = edge_at(eidx, e, is64);
        int d  = edge_at(eidx, (long long)E + e, is64);
        int b  = d >> BINSH;
        int pos = lbase[b] + atomicAdd(&lcur[b], 1);
        ibuf[pos] = make_int2(sN, d);
    }
}

// ---------------- per-bin exact sort; computes rp + dis; ep = src only ----------------
__global__ __launch_bounds__(256) void binsort2_kernel(const int2* __restrict__ ibuf,
                                                       const int* __restrict__ binrp,
                                                       int* __restrict__ rp,
                                                       float* __restrict__ dis,
                                                       int* __restrict__ ep, int N) {
    const int b  = blockIdx.x;
    const int d0 = b << BINSH;
    const int dc = min(1 << BINSH, N - d0);
    __shared__ int lcnt[1 << BINSH];
    __shared__ int lofs[1 << BINSH];
    __shared__ int s2[256];
    const int t = threadIdx.x;
    lcnt[t] = 0; lcnt[t + 256] = 0;
    __syncthreads();
    const int ib0 = binrp[b], ib1 = binrp[b + 1];
    const int nE  = ib1 - ib0;
    for (int i = t; i < nE; i += 256) {
        int2 sd = ibuf[ib0 + i];
        atomicAdd(&lcnt[sd.y - d0], 1);
    }
    __syncthreads();
    const int c0 = lcnt[2 * t], c1 = lcnt[2 * t + 1];
    const int pair = c0 + c1;
    s2[t] = pair;
    __syncthreads();
    for (int off = 1; off < 256; off <<= 1) {
        int x = (t >= off) ? s2[t - off] : 0;
        __syncthreads();
        s2[t] += x;
        __syncthreads();
    }
    const int pexcl = s2[t] - pair;
    if (2 * t < dc) {
        rp[d0 + 2 * t + 1] = ib0 + pexcl + c0;
        dis[d0 + 2 * t]    = rsqrtf((float)c0 + 1.0f);
    }
    if (2 * t + 1 < dc) {
        rp[d0 + 2 * t + 2] = ib0 + pexcl + pair;
        dis[d0 + 2 * t + 1] = rsqrtf((float)c1 + 1.0f);
    }
    if (b == 0 && t == 0) rp[0] = 0;
    lofs[2 * t]     = pexcl;
    lofs[2 * t + 1] = pexcl + c0;
    __syncthreads();
    for (int i = t; i < nE; i += 256) {
        int2 sd = ibuf[ib0 + i];
        int dl  = sd.y - d0;
        int pos = ib0 + atomicAdd(&lofs[dl], 1);
        ep[pos] = sd.x;
    }
}

// ---------------- fragment loaders ----------------
__device__ __forceinline__ void load8(const float* p, float* f) {
    float4 v0 = ((const float4*)p)[0];
    float4 v1 = ((const float4*)p)[1];
    f[0] = v0.x; f[1] = v0.y; f[2] = v0.z; f[3] = v0.w;
    f[4] = v1.x; f[5] = v1.y; f[6] = v1.z; f[7] = v1.w;
}
__device__ __forceinline__ void load8(const __hip_bfloat16* p, float* f) {
    uint4 v = *(const uint4*)p;
    f[0] = u2f(v.x << 16); f[1] = u2f(v.x & 0xffff0000u);
    f[2] = u2f(v.y << 16); f[3] = u2f(v.y & 0xffff0000u);
    f[4] = u2f(v.z << 16); f[5] = u2f(v.z & 0xffff0000u);
    f[6] = u2f(v.w << 16); f[7] = u2f(v.w & 0xffff0000u);
}

// ---------------- MFMA GEMM with fused BN finalize+apply ----------------
template <int DOUT, bool BN, typename TH>
__global__ __launch_bounds__(256) void mfma_gemm_kernel(const TH* __restrict__ H,
                                                        const __hip_bfloat16* __restrict__ Wt,
                                                        const float* __restrict__ stats,
                                                        const float* __restrict__ g,
                                                        const float* __restrict__ be,
                                                        float invN,
                                                        __hip_bfloat16* __restrict__ out, int N) {
    constexpr int NCT = DOUT / 16;
    constexpr int LDW = 136;
    __shared__ __hip_bfloat16 sWt[DOUT * LDW];
    __shared__ float sBN[256];
    const int t = threadIdx.x;
    for (int i = t; i < DOUT * 16; i += 256) {
        int row = i >> 4, seg = i & 15;
        *(uint4*)&sWt[row * LDW + seg * 8] = ((const uint4*)Wt)[i];
    }
    if (BN && t < 128) {
        float mu  = stats[t] * invN;
        float var = stats[128 + t] * invN - mu * mu;
        float sc  = g[t] * rsqrtf(var + BN_EPS);
        sBN[t]       = sc;
        sBN[128 + t] = be[t] - mu * sc;
    }
    __syncthreads();
    const int lane = t & 63, wid = t >> 6;
    const int kq = lane >> 4, mrow = lane & 15;
    const int grow = blockIdx.x * 64 + wid * 16 + mrow;
    const int lrow = min(grow, N - 1);
    bf16x8v afrag[4];
#pragma unroll
    for (int ks = 0; ks < 4; ++ks) {
        const int k0 = ks * 32 + kq * 8;
        float f[8];
        load8(H + (size_t)lrow * 128 + k0, f);
        if (BN) {
            float4 s0 = *(const float4*)&sBN[k0];
            float4 s1 = *(const float4*)&sBN[k0 + 4];
            float4 h0 = *(const float4*)&sBN[128 + k0];
            float4 h1 = *(const float4*)&sBN[128 + k0 + 4];
            f[0] = fmaxf(fmaf(f[0], s0.x, h0.x), 0.f);
            f[1] = fmaxf(fmaf(f[1], s0.y, h0.y), 0.f);
            f[2] = fmaxf(fmaf(f[2], s0.z, h0.z), 0.f);
            f[3] = fmaxf(fmaf(f[3], s0.w, h0.w), 0.f);
            f[4] = fmaxf(fmaf(f[4], s1.x, h1.x), 0.f);
            f[5] = fmaxf(fmaf(f[5], s1.y, h1.y), 0.f);
            f[6] = fmaxf(fmaf(f[6], s1.z, h1.z), 0.f);
            f[7] = fmaxf(fmaf(f[7], s1.w, h1.w), 0.f);
        }
        bf16x8v a;
#pragma unroll
        for (int j = 0; j < 8; ++j) a[j] = (short)f2bf(f[j]);
        afrag[ks] = a;
    }
    f32x4v acc[NCT];
#pragma unroll
    for (int ct = 0; ct < NCT; ++ct) acc[ct] = (f32x4v){0.f, 0.f, 0.f, 0.f};
#pragma unroll
    for (int ct = 0; ct < NCT; ++ct) {
#pragma unroll
        for (int ks = 0; ks < 4; ++ks) {
            bf16x8v b = *(const bf16x8v*)&sWt[(ct * 16 + mrow) * LDW + ks * 32 + kq * 8];
            acc[ct] = __builtin_amdgcn_mfma_f32_16x16x32_bf16(afrag[ks], b, acc[ct], 0, 0, 0);
        }
    }
#pragma unroll
    for (int r = 0; r < 4; ++r) {
        int orow = blockIdx.x * 64 + wid * 16 + kq * 4 + r;
        if (orow < N) {
            __hip_bfloat16* op = out + (size_t)orow * DOUT + mrow;
#pragma unroll
            for (int ct = 0; ct < NCT; ++ct) {
                union { unsigned short u; __hip_bfloat16 h; } cv;
                cv.u = f2bf(acc[ct][r]);
                op[ct * 16] = cv.h;
            }
        }
    }
}

// ---------------- aggregation: 8 cols/thread, factored weights, optional BN partials ----------------
// out[n] = dis[n] * ( hw[n]*dis[n] + Σ_e hw[src_e]*dis[src_e] ) + bias
__device__ __forceinline__ void acc8(float* a, uint4 v, float w) {
    a[0] += u2f(v.x << 16) * w;  a[1] += u2f(v.x & 0xffff0000u) * w;
    a[2] += u2f(v.y << 16) * w;  a[3] += u2f(v.y & 0xffff0000u) * w;
    a[4] += u2f(v.z << 16) * w;  a[5] += u2f(v.z & 0xffff0000u) * w;
    a[6] += u2f(v.w << 16) * w;  a[7] += u2f(v.w & 0xffff0000u) * w;
}

template <int D, bool OUTBF, bool STATS>
__global__ __launch_bounds__(256) void agg_kernel(const __hip_bfloat16* __restrict__ hw,
                                                  const int* __restrict__ rp,
                                                  const int* __restrict__ ep,
                                                  const float* __restrict__ dis,
                                                  const float* __restrict__ bias,
                                                  void* __restrict__ outv,
                                                  float* __restrict__ partial, int N) {
    constexpr int LPR = D / 8;              // lanes per row, 8 cols each
    const int t = threadIdx.x;
    const int gtid = blockIdx.x * 256 + t;
    const int idx  = gtid / LPR;
    const int lane = gtid % LPR;
    const bool valid = idx < N;
    if (!STATS && !valid) return;
    const int n = valid ? idx : (N - 1);
    const uint4* hw8 = (const uint4*)hw;
    float a[8] = {0.f, 0.f, 0.f, 0.f, 0.f, 0.f, 0.f, 0.f};
    const float dn = dis[n];
    uint4 hv = hw8[(size_t)n * LPR + lane];
    acc8(a, hv, dn);                        // self term (×dn later => dis²)
    int e0 = rp[n], e1 = rp[n + 1];
    int e = e0;
    for (; e + 4 <= e1; e += 4) {
        int p0 = ep[e + 0];
        int p1 = ep[e + 1];
        int p2 = ep[e + 2];
        int p3 = ep[e + 3];
        uint4 v0 = hw8[(size_t)p0 * LPR + lane];
        uint4 v1 = hw8[(size_t)p1 * LPR + lane];
        uint4 v2 = hw8[(size_t)p2 * LPR + lane];
        uint4 v3 = hw8[(size_t)p3 * LPR + lane];
        acc8(a, v0, dis[p0]);
        acc8(a, v1, dis[p1]);
        acc8(a, v2, dis[p2]);
        acc8(a, v3, dis[p3]);
    }
    for (; e < e1; ++e) {
        int p = ep[e];
        uint4 v = hw8[(size_t)p * LPR + lane];
        acc8(a, v, dis[p]);
    }
    float4 b0 = *(const float4*)(bias + lane * 8);
    float4 b1 = *(const float4*)(bias + lane * 8 + 4);
    a[0] = fmaf(a[0], dn, b0.x); a[1] = fmaf(a[1], dn, b0.y);
    a[2] = fmaf(a[2], dn, b0.z); a[3] = fmaf(a[3], dn, b0.w);
    a[4] = fmaf(a[4], dn, b1.x); a[5] = fmaf(a[5], dn, b1.y);
    a[6] = fmaf(a[6], dn, b1.z); a[7] = fmaf(a[7], dn, b1.w);
    if (STATS) {
        // per-block column partial sums (non-atomic!), reduced by red_kernel
        __shared__ float ls[16][128];       // D=128 only: 16 rows x 128 cols
        const int r16 = t >> 4;
#pragma unroll
        for (int j = 0; j < 8; ++j) ls[r16][lane * 8 + j] = valid ? a[j] : 0.f;
        __syncthreads();
        if (t < 128) {
            float s = 0.f, q = 0.f;
#pragma unroll
            for (int r = 0; r < 16; ++r) {
                float v = ls[r][t];
                s += v;
                q += v * v;
            }
            partial[(size_t)blockIdx.x * 256 + t]       = s;
            partial[(size_t)blockIdx.x * 256 + 128 + t] = q;
        }
    }
    if (valid) {
        if (OUTBF) {
            uint4 o;
            o.x = (unsigned)f2bf(a[0]) | ((unsigned)f2bf(a[1]) << 16);
            o.y = (unsigned)f2bf(a[2]) | ((unsigned)f2bf(a[3]) << 16);
            o.z = (unsigned)f2bf(a[4]) | ((unsigned)f2bf(a[5]) << 16);
            o.w = (unsigned)f2bf(a[6]) | ((unsigned)f2bf(a[7]) << 16);
            ((uint4*)outv)[(size_t)n * LPR + lane] = o;
        } else {
            float4* op = (float4*)outv + ((size_t)n * D + lane * 8) / 4;
            op[0] = make_float4(a[0], a[1], a[2], a[3]);
            op[1] = make_float4(a[4], a[5], a[6], a[7]);
        }
    }
}

// ---------------- partial reduction -> stats (sum[128], sumsq[128]) ----------------
__global__ __launch_bounds__(256) void red_kernel(const float* __restrict__ partial,
                                                  float* __restrict__ stats, int nb) {
    const int t = threadIdx.x;
    const int per = (nb + gridDim.x - 1) / gridDim.x;
    const int r0 = blockIdx.x * per;
    const int r1 = min(r0 + per, nb);
    float s = 0.f;
    for (int r = r0; r < r1; ++r) s += partial[(size_t)r * 256 + t];
    atomicAdd(&stats[t], s);
}

// ---------------- host launch ----------------
extern "C" void kernel_launch(void* const* d_in, const int* in_sizes, int n_in,
                              void* d_out, int out_size, void* d_ws, size_t ws_size,
                              hipStream_t stream) {
    const float* x   = (const float*)d_in[0];
    const void*  eix = d_in[1];
    const float* W1  = (const float*)d_in[2];
    const float* b1  = (const float*)d_in[3];
    const float* g1  = (const float*)d_in[4];
    const float* be1 = (const float*)d_in[5];
    const float* W2  = (const float*)d_in[6];
    const float* b2  = (const float*)d_in[7];
    const float* g2  = (const float*)d_in[8];
    const float* be2 = (const float*)d_in[9];
    const float* W3  = (const float*)d_in[10];
    const float* b3  = (const float*)d_in[11];
    float* outp = (float*)d_out;

    const int N = in_sizes[0] / 128;
    const int E = in_sizes[1] / 2;
    const int NB = (N + (1 << BINSH) - 1) >> BINSH;

    char* base = (char*)d_ws;
    size_t off = 0;
    auto alloc = [&](size_t bytes) -> char* {
        char* p = base + off;
        off = (off + bytes + 255) & ~(size_t)255;
        return p;
    };
    __hip_bfloat16* A = (__hip_bfloat16*)alloc((size_t)N * 128 * 2);
    __hip_bfloat16* B = (__hip_bfloat16*)alloc((size_t)N * 128 * 2);
    int*   rp      = (int*)alloc((size_t)(N + 1) * 4);
    float* dis     = (float*)alloc((size_t)N * 4);
    int*   ep      = (int*)alloc((size_t)E * 4);
    int2*  ibuf    = (int2*)alloc((size_t)E * 8);   // dead after binsort2; reused as partials
    int*   hist2dT = (int*)alloc((size_t)MAXNB * NBLK * 4);
    int*   binrp   = (int*)alloc((MAXNB + 1) * 4);
    // contiguous zero-region: binhist (pads to 1024) + stats1 (1024) + stats2 (1024)
    int*   binhist = (int*)alloc(MAXNB * 4);
    float* stats1  = (float*)alloc(256 * 4);
    float* stats2  = (float*)alloc(256 * 4);
    __hip_bfloat16* wt1 = (__hip_bfloat16*)alloc(128 * 128 * 2);
    __hip_bfloat16* wt2 = (__hip_bfloat16*)alloc(128 * 128 * 2);
    __hip_bfloat16* wt3 = (__hip_bfloat16*)alloc(64 * 128 * 2);
    (void)ws_size; (void)n_in; (void)out_size;

    const int per_block   = (E + NBLK - 1) / NBLK;
    const int gemm_grid   = (N + 63) / 64;
    const int agg128_grid = (int)(((long long)N * 16 + 255) / 256);
    const int agg64_grid  = (int)(((long long)N * 8 + 255) / 256);
    const float invN = 1.0f / (float)N;

    // partials alias the dead ibuf region (agg128_grid*256*4 = 6.4 MB each, ibuf = 12.8 MB)
    float* partial1 = (float*)ibuf;
    float* partial2 = (float*)ibuf + (size_t)agg128_grid * 256;

    // ---- graph preprocessing (5 dispatches incl. weight prep) ----
    hipMemsetAsync(binhist, 0, 3 * 1024, stream);   // binhist + stats1 + stats2
    histA_kernel<<<NBLK + 160, 256, 0, stream>>>(eix, hist2dT, binhist,
                                                 W1, W2, W3, wt1, wt2, wt3, E, NB, per_block);
    colscan_kernel<<<NB, 256, 0, stream>>>(hist2dT, binhist, binrp, NB);
    passB_kernel<<<NBLK, 256, 0, stream>>>(eix, hist2dT, ibuf, E, NB, per_block);
    binsort2_kernel<<<NB, 256, 0, stream>>>(ibuf, binrp, rp, dis, ep, N);

    // ---- layer 1 ----
    mfma_gemm_kernel<128, false, float><<<gemm_grid, 256, 0, stream>>>(
        x, wt1, nullptr, nullptr, nullptr, 0.f, A, N);
    agg_kernel<128, true, true><<<agg128_grid, 256, 0, stream>>>(
        A, rp, ep, dis, b1, B, partial1, N);
    red_kernel<<<32, 256, 0, stream>>>(partial1, stats1, agg128_grid);

    // ---- layer 2 (BN finalize fused into gemm) ----
    mfma_gemm_kernel<128, true, __hip_bfloat16><<<gemm_grid, 256, 0, stream>>>(
        B, wt2, stats1, g1, be1, invN, A, N);
    agg_kernel<128, true, true><<<agg128_grid, 256, 0, stream>>>(
        A, rp, ep, dis, b2, B, partial2, N);
    red_kernel<<<32, 256, 0, stream>>>(partial2, stats2, agg128_grid);

    // ---- layer 3 ----
    mfma_gemm_kernel<64, true, __hip_bfloat16><<<gemm_grid, 256, 0, stream>>>(
        B, wt3, stats2, g2, be2, invN, A, N);
    agg_kernel<64, false, false><<<agg64_grid, 256, 0, stream>>>(
        A, rp, ep, dis, b3, outp, nullptr, N);
}

// Round 12
// 360.170 us; speedup vs baseline: 1.0323x; 1.0134x over previous
//
#include <hip/hip_runtime.h>
#include <hip/hip_bf16.h>

#define BN_EPS 1e-5f
#define BINSH 9
#define MAXNB 200
#define NBLK 256
#define BIN_CAP 8960

typedef __attribute__((ext_vector_type(8))) short bf16x8v;
typedef __attribute__((ext_vector_type(4))) float f32x4v;

__device__ __forceinline__ float u2f(unsigned x) { return __uint_as_float(x); }
__device__ __forceinline__ unsigned short f2bf(float f) {
    union { __hip_bfloat16 h; unsigned short u; } cv;
    cv.h = __float2bfloat16(f);
    return cv.u;
}

__device__ __forceinline__ int edge_at(const void* p, long long i, int is64) {
    return is64 ? (int)((const long long*)p)[i] : ((const int*)p)[i];
}

__device__ __forceinline__ void detect_is64(const void* eidx, int* sflag, int t) {
    if (t == 0) {
        const int* e32 = (const int*)eidx;
        int nz = 0;
        for (int i = 0; i < 64; ++i) nz += (e32[2 * i + 1] != 0);
        *sflag = (nz == 0) ? 1 : 0;
    }
}

// ---------------- pass A: per-block bin histogram + (tail blocks) weight transpose ----------------
__global__ __launch_bounds__(256) void histA_kernel(const void* __restrict__ eidx,
                                                    int* __restrict__ hist2dT,
                                                    int* __restrict__ binhist,
                                                    const float* __restrict__ W1,
                                                    const float* __restrict__ W2,
                                                    const float* __restrict__ W3,
                                                    __hip_bfloat16* __restrict__ wt1,
                                                    __hip_bfloat16* __restrict__ wt2,
                                                    __hip_bfloat16* __restrict__ wt3,
                                                    int E, int NB, int per_block) {
    const int t = threadIdx.x;
    if (blockIdx.x >= NBLK) {
        int i = (blockIdx.x - NBLK) * 256 + t;
        if (i < 16384) {
            int k = i >> 7, c = i & 127;
            wt1[c * 128 + k] = __float2bfloat16(W1[i]);
        } else if (i < 32768) {
            int j = i - 16384, k = j >> 7, c = j & 127;
            wt2[c * 128 + k] = __float2bfloat16(W2[j]);
        } else if (i < 40960) {
            int j = i - 32768, k = j >> 6, c = j & 63;
            wt3[c * 128 + k] = __float2bfloat16(W3[j]);
        }
        return;
    }
    __shared__ int lh[MAXNB];
    __shared__ int sflag;
    detect_is64(eidx, &sflag, t);
    for (int i = t; i < NB; i += 256) lh[i] = 0;
    __syncthreads();
    const int is64 = sflag;
    long long base = (long long)blockIdx.x * per_block;
    long long lim  = base + per_block;
    if (lim > E) lim = E;
    for (long long e = base + t; e < lim; e += 256) {
        int d = edge_at(eidx, (long long)E + e, is64);
        atomicAdd(&lh[d >> BINSH], 1);
    }
    __syncthreads();
    for (int i = t; i < NB; i += 256) {
        hist2dT[i * NBLK + blockIdx.x] = lh[i];
        atomicAdd(&binhist[i], lh[i]);
    }
}

// ---------------- colscan (absorbs binscan): per-bin base + column prefix ----------------
__global__ __launch_bounds__(256) void colscan_kernel(int* __restrict__ hist2dT,
                                                      const int* __restrict__ binhist,
                                                      int* __restrict__ binrp, int NB) {
    __shared__ int s[256];
    __shared__ int sbase;
    const int b = blockIdx.x;
    const int t = threadIdx.x;
    s[t] = (t < b) ? binhist[t] : 0;
    __syncthreads();
    for (int off = 128; off > 0; off >>= 1) {
        if (t < off) s[t] += s[t + off];
        __syncthreads();
    }
    if (t == 0) sbase = s[0];
    __syncthreads();
    const int base = sbase;
    if (t == 0) {
        binrp[b] = base;
        if (b == NB - 1) binrp[NB] = base + binhist[b];
    }
    int v = hist2dT[b * NBLK + t];
    s[t] = v;
    __syncthreads();
    for (int off = 1; off < 256; off <<= 1) {
        int x = (t >= off) ? s[t - off] : 0;
        __syncthreads();
        s[t] += x;
        __syncthreads();
    }
    hist2dT[b * NBLK + t] = base + s[t] - v;
}

// ---------------- pass B: edge-parallel scatter into reserved ranges ----------------
__global__ __launch_bounds__(256) void passB_kernel(const void* __restrict__ eidx,
                                                    const int* __restrict__ hist2dT,
                                                    int2* __restrict__ ibuf,
                                                    int E, int NB, int per_block) {
    __shared__ int lbase[MAXNB];
    __shared__ int lcur[MAXNB];
    __shared__ int sflag;
    const int t = threadIdx.x;
    detect_is64(eidx, &sflag, t);
    for (int i = t; i < NB; i += 256) {
        lbase[i] = hist2dT[i * NBLK + blockIdx.x];
        lcur[i]  = 0;
    }
    __syncthreads();
    const int is64 = sflag;
    long long base = (long long)blockIdx.x * per_block;
    long long lim  = base + per_block;
    if (lim > E) lim = E;
    for (long long e = base + t; e < lim; e += 256) {
        int sN = edge_at(eidx, e, is64);
        int d  = edge_at(eidx, (long long)E + e, is64);
        int b  = d >> BINSH;
        int pos = lbase[b] + atomicAdd(&lcur[b], 1);
        ibuf[pos] = make_int2(sN, d);
    }
}

// ---------------- per-bin exact sort (coalesced-write variant); computes rp + dis ----------------
__global__ __launch_bounds__(256) void binsort2_kernel(const int2* __restrict__ ibuf,
                                                       const int* __restrict__ binrp,
                                                       int* __restrict__ rp,
                                                       float* __restrict__ dis,
                                                       int* __restrict__ ep, int N) {
    const int b  = blockIdx.x;
    const int d0 = b << BINSH;
    const int dc = min(1 << BINSH, N - d0);
    __shared__ int lcnt[1 << BINSH];
    __shared__ int lofs[1 << BINSH];
    __shared__ int s2[256];
    __shared__ unsigned short sperm[BIN_CAP];
    const int t = threadIdx.x;
    lcnt[t] = 0; lcnt[t + 256] = 0;
    __syncthreads();
    const int ib0 = binrp[b], ib1 = binrp[b + 1];
    const int nE  = ib1 - ib0;
    for (int i = t; i < nE; i += 256) {
        int2 sd = ibuf[ib0 + i];
        atomicAdd(&lcnt[sd.y - d0], 1);
    }
    __syncthreads();
    const int c0 = lcnt[2 * t], c1 = lcnt[2 * t + 1];
    const int pair = c0 + c1;
    s2[t] = pair;
    __syncthreads();
    for (int off = 1; off < 256; off <<= 1) {
        int x = (t >= off) ? s2[t - off] : 0;
        __syncthreads();
        s2[t] += x;
        __syncthreads();
    }
    const int pexcl = s2[t] - pair;
    if (2 * t < dc) {
        rp[d0 + 2 * t + 1] = ib0 + pexcl + c0;
        dis[d0 + 2 * t]    = rsqrtf((float)c0 + 1.0f);
    }
    if (2 * t + 1 < dc) {
        rp[d0 + 2 * t + 2] = ib0 + pexcl + pair;
        dis[d0 + 2 * t + 1] = rsqrtf((float)c1 + 1.0f);
    }
    if (b == 0 && t == 0) rp[0] = 0;
    lofs[2 * t]     = pexcl;
    lofs[2 * t + 1] = pexcl + c0;
    __syncthreads();
    if (nE <= BIN_CAP) {
        // phase 1: permutation into LDS (scattered LDS, cheap)
        for (int i = t; i < nE; i += 256) {
            int dl = ibuf[ib0 + i].y - d0;
            int pos = atomicAdd(&lofs[dl], 1);
            sperm[pos] = (unsigned short)i;
        }
        __syncthreads();
        // phase 2: coalesced global writes, cached random reads
        for (int j = t; j < nE; j += 256)
            ep[ib0 + j] = ibuf[ib0 + (int)sperm[j]].x;
    } else {
        for (int i = t; i < nE; i += 256) {
            int2 sd = ibuf[ib0 + i];
            int pos = ib0 + atomicAdd(&lofs[sd.y - d0], 1);
            ep[pos] = sd.x;
        }
    }
}

// ---------------- fragment loaders ----------------
__device__ __forceinline__ void load8(const float* p, float* f) {
    float4 v0 = ((const float4*)p)[0];
    float4 v1 = ((const float4*)p)[1];
    f[0] = v0.x; f[1] = v0.y; f[2] = v0.z; f[3] = v0.w;
    f[4] = v1.x; f[5] = v1.y; f[6] = v1.z; f[7] = v1.w;
}
__device__ __forceinline__ void load8(const __hip_bfloat16* p, float* f) {
    uint4 v = *(const uint4*)p;
    f[0] = u2f(v.x << 16); f[1] = u2f(v.x & 0xffff0000u);
    f[2] = u2f(v.y << 16); f[3] = u2f(v.y & 0xffff0000u);
    f[4] = u2f(v.z << 16); f[5] = u2f(v.z & 0xffff0000u);
    f[6] = u2f(v.w << 16); f[7] = u2f(v.w & 0xffff0000u);
}

// ---------------- MFMA GEMM: 256 rows/block, Wt staged once; fused BN finalize+apply ----------------
template <int DOUT, bool BN, typename TH>
__global__ __launch_bounds__(256) void mfma_gemm_kernel(const TH* __restrict__ H,
                                                        const __hip_bfloat16* __restrict__ Wt,
                                                        const float* __restrict__ stats,
                                                        const float* __restrict__ g,
                                                        const float* __restrict__ be,
                                                        float invN,
                                                        __hip_bfloat16* __restrict__ out, int N) {
    constexpr int NCT = DOUT / 16;
    constexpr int LDW = 136;
    __shared__ __hip_bfloat16 sWt[DOUT * LDW];
    __shared__ float sBN[256];
    const int t = threadIdx.x;
    for (int i = t; i < DOUT * 16; i += 256) {
        int row = i >> 4, seg = i & 15;
        *(uint4*)&sWt[row * LDW + seg * 8] = ((const uint4*)Wt)[i];
    }
    if (BN && t < 128) {
        float mu  = stats[t] * invN;
        float var = stats[128 + t] * invN - mu * mu;
        float sc  = g[t] * rsqrtf(var + BN_EPS);
        sBN[t]       = sc;
        sBN[128 + t] = be[t] - mu * sc;
    }
    __syncthreads();
    const int lane = t & 63, wid = t >> 6;
    const int kq = lane >> 4, mrow = lane & 15;
#pragma unroll
    for (int gq = 0; gq < 4; ++gq) {
        const int rbase = blockIdx.x * 256 + wid * 64 + gq * 16;
        if (rbase >= N) break;
        const int lrow = min(rbase + mrow, N - 1);
        bf16x8v afrag[4];
#pragma unroll
        for (int ks = 0; ks < 4; ++ks) {
            const int k0 = ks * 32 + kq * 8;
            float f[8];
            load8(H + (size_t)lrow * 128 + k0, f);
            if (BN) {
                float4 s0 = *(const float4*)&sBN[k0];
                float4 s1 = *(const float4*)&sBN[k0 + 4];
                float4 h0 = *(const float4*)&sBN[128 + k0];
                float4 h1 = *(const float4*)&sBN[128 + k0 + 4];
                f[0] = fmaxf(fmaf(f[0], s0.x, h0.x), 0.f);
                f[1] = fmaxf(fmaf(f[1], s0.y, h0.y), 0.f);
                f[2] = fmaxf(fmaf(f[2], s0.z, h0.z), 0.f);
                f[3] = fmaxf(fmaf(f[3], s0.w, h0.w), 0.f);
                f[4] = fmaxf(fmaf(f[4], s1.x, h1.x), 0.f);
                f[5] = fmaxf(fmaf(f[5], s1.y, h1.y), 0.f);
                f[6] = fmaxf(fmaf(f[6], s1.z, h1.z), 0.f);
                f[7] = fmaxf(fmaf(f[7], s1.w, h1.w), 0.f);
            }
            bf16x8v a;
#pragma unroll
            for (int j = 0; j < 8; ++j) a[j] = (short)f2bf(f[j]);
            afrag[ks] = a;
        }
        f32x4v acc[NCT];
#pragma unroll
        for (int ct = 0; ct < NCT; ++ct) acc[ct] = (f32x4v){0.f, 0.f, 0.f, 0.f};
#pragma unroll
        for (int ct = 0; ct < NCT; ++ct) {
#pragma unroll
            for (int ks = 0; ks < 4; ++ks) {
                bf16x8v bb = *(const bf16x8v*)&sWt[(ct * 16 + mrow) * LDW + ks * 32 + kq * 8];
                acc[ct] = __builtin_amdgcn_mfma_f32_16x16x32_bf16(afrag[ks], bb, acc[ct], 0, 0, 0);
            }
        }
#pragma unroll
        for (int r = 0; r < 4; ++r) {
            int orow = rbase + kq * 4 + r;
            if (orow < N) {
                __hip_bfloat16* op = out + (size_t)orow * DOUT + mrow;
#pragma unroll
                for (int ct = 0; ct < NCT; ++ct) {
                    union { unsigned short u; __hip_bfloat16 h; } cv;
                    cv.u = f2bf(acc[ct][r]);
                    op[ct * 16] = cv.h;
                }
            }
        }
    }
}

// ---------------- aggregation: 8 cols/thread, factored weights, optional BN partials ----------------
__device__ __forceinline__ void acc8(float* a, uint4 v, float w) {
    a[0] += u2f(v.x << 16) * w;  a[1] += u2f(v.x & 0xffff0000u) * w;
    a[2] += u2f(v.y << 16) * w;  a[3] += u2f(v.y & 0xffff0000u) * w;
    a[4] += u2f(v.z << 16) * w;  a[5] += u2f(v.z & 0xffff0000u) * w;
    a[6] += u2f(v.w << 16) * w;  a[7] += u2f(v.w & 0xffff0000u) * w;
}

template <int D, bool OUTBF, bool STATS>
__global__ __launch_bounds__(256) void agg_kernel(const __hip_bfloat16* __restrict__ hw,
                                                  const int* __restrict__ rp,
                                                  const int* __restrict__ ep,
                                                  const float* __restrict__ dis,
                                                  const float* __restrict__ bias,
                                                  void* __restrict__ outv,
                                                  float* __restrict__ partial, int N) {
    constexpr int LPR = D / 8;
    const int t = threadIdx.x;
    const int gtid = blockIdx.x * 256 + t;
    const int idx  = gtid / LPR;
    const int lane = gtid % LPR;
    const bool valid = idx < N;
    if (!STATS && !valid) return;
    const int n = valid ? idx : (N - 1);
    const uint4* hw8 = (const uint4*)hw;
    float a[8] = {0.f, 0.f, 0.f, 0.f, 0.f, 0.f, 0.f, 0.f};
    const float dn = dis[n];
    uint4 hv = hw8[(size_t)n * LPR + lane];
    acc8(a, hv, dn);
    int e0 = rp[n], e1 = rp[n + 1];
    int e = e0;
    for (; e + 4 <= e1; e += 4) {
        int p0 = ep[e + 0];
        int p1 = ep[e + 1];
        int p2 = ep[e + 2];
        int p3 = ep[e + 3];
        uint4 v0 = hw8[(size_t)p0 * LPR + lane];
        uint4 v1 = hw8[(size_t)p1 * LPR + lane];
        uint4 v2 = hw8[(size_t)p2 * LPR + lane];
        uint4 v3 = hw8[(size_t)p3 * LPR + lane];
        acc8(a, v0, dis[p0]);
        acc8(a, v1, dis[p1]);
        acc8(a, v2, dis[p2]);
        acc8(a, v3, dis[p3]);
    }
    for (; e < e1; ++e) {
        int p = ep[e];
        uint4 v = hw8[(size_t)p * LPR + lane];
        acc8(a, v, dis[p]);
    }
    float4 b0 = *(const float4*)(bias + lane * 8);
    float4 b1 = *(const float4*)(bias + lane * 8 + 4);
    a[0] = fmaf(a[0], dn, b0.x); a[1] = fmaf(a[1], dn, b0.y);
    a[2] = fmaf(a[2], dn, b0.z); a[3] = fmaf(a[3], dn, b0.w);
    a[4] = fmaf(a[4], dn, b1.x); a[5] = fmaf(a[5], dn, b1.y);
    a[6] = fmaf(a[6], dn, b1.z); a[7] = fmaf(a[7], dn, b1.w);
    if (STATS) {
        __shared__ float ls[16][128];
        const int r16 = t >> 4;
#pragma unroll
        for (int j = 0; j < 8; ++j) ls[r16][lane * 8 + j] = valid ? a[j] : 0.f;
        __syncthreads();
        if (t < 128) {
            float s = 0.f, q = 0.f;
#pragma unroll
            for (int r = 0; r < 16; ++r) {
                float v = ls[r][t];
                s += v;
                q += v * v;
            }
            partial[(size_t)blockIdx.x * 256 + t]       = s;
            partial[(size_t)blockIdx.x * 256 + 128 + t] = q;
        }
    }
    if (valid) {
        if (OUTBF) {
            uint4 o;
            o.x = (unsigned)f2bf(a[0]) | ((unsigned)f2bf(a[1]) << 16);
            o.y = (unsigned)f2bf(a[2]) | ((unsigned)f2bf(a[3]) << 16);
            o.z = (unsigned)f2bf(a[4]) | ((unsigned)f2bf(a[5]) << 16);
            o.w = (unsigned)f2bf(a[6]) | ((unsigned)f2bf(a[7]) << 16);
            ((uint4*)outv)[(size_t)n * LPR + lane] = o;
        } else {
            float4* op = (float4*)outv + ((size_t)n * D + lane * 8) / 4;
            op[0] = make_float4(a[0], a[1], a[2], a[3]);
            op[1] = make_float4(a[4], a[5], a[6], a[7]);
        }
    }
}

// ---------------- partial reduction -> stats (sum[128], sumsq[128]) ----------------
__global__ __launch_bounds__(256) void red_kernel(const float* __restrict__ partial,
                                                  float* __restrict__ stats, int nb) {
    const int t = threadIdx.x;
    const int per = (nb + gridDim.x - 1) / gridDim.x;
    const int r0 = blockIdx.x * per;
    const int r1 = min(r0 + per, nb);
    float s = 0.f;
    for (int r = r0; r < r1; ++r) s += partial[(size_t)r * 256 + t];
    atomicAdd(&stats[t], s);
}

// ---------------- host launch ----------------
extern "C" void kernel_launch(void* const* d_in, const int* in_sizes, int n_in,
                              void* d_out, int out_size, void* d_ws, size_t ws_size,
                              hipStream_t stream) {
    const float* x   = (const float*)d_in[0];
    const void*  eix = d_in[1];
    const float* W1  = (const float*)d_in[2];
    const float* b1  = (const float*)d_in[3];
    const float* g1  = (const float*)d_in[4];
    const float* be1 = (const float*)d_in[5];
    const float* W2  = (const float*)d_in[6];
    const float* b2  = (const float*)d_in[7];
    const float* g2  = (const float*)d_in[8];
    const float* be2 = (const float*)d_in[9];
    const float* W3  = (const float*)d_in[10];
    const float* b3  = (const float*)d_in[11];
    float* outp = (float*)d_out;

    const int N = in_sizes[0] / 128;
    const int E = in_sizes[1] / 2;
    const int NB = (N + (1 << BINSH) - 1) >> BINSH;

    char* base = (char*)d_ws;
    size_t off = 0;
    auto alloc = [&](size_t bytes) -> char* {
        char* p = base + off;
        off = (off + bytes + 255) & ~(size_t)255;
        return p;
    };
    __hip_bfloat16* A = (__hip_bfloat16*)alloc((size_t)N * 128 * 2);
    __hip_bfloat16* B = (__hip_bfloat16*)alloc((size_t)N * 128 * 2);
    int*   rp      = (int*)alloc((size_t)(N + 1) * 4);
    float* dis     = (float*)alloc((size_t)N * 4);
    int*   ep      = (int*)alloc((size_t)E * 4);
    int2*  ibuf    = (int2*)alloc((size_t)E * 8);   // dead after binsort2; reused as partials
    int*   hist2dT = (int*)alloc((size_t)MAXNB * NBLK * 4);
    int*   binrp   = (int*)alloc((MAXNB + 1) * 4);
    int*   binhist = (int*)alloc(MAXNB * 4);
    float* stats1  = (float*)alloc(256 * 4);
    float* stats2  = (float*)alloc(256 * 4);
    __hip_bfloat16* wt1 = (__hip_bfloat16*)alloc(128 * 128 * 2);
    __hip_bfloat16* wt2 = (__hip_bfloat16*)alloc(128 * 128 * 2);
    __hip_bfloat16* wt3 = (__hip_bfloat16*)alloc(64 * 128 * 2);
    (void)ws_size; (void)n_in; (void)out_size;

    const int per_block   = (E + NBLK - 1) / NBLK;
    const int gemm_grid   = (N + 255) / 256;
    const int agg128_grid = (int)(((long long)N * 16 + 255) / 256);
    const int agg64_grid  = (int)(((long long)N * 8 + 255) / 256);
    const float invN = 1.0f / (float)N;

    float* partial1 = (float*)ibuf;
    float* partial2 = (float*)ibuf + (size_t)agg128_grid * 256;

    // ---- graph preprocessing ----
    hipMemsetAsync(binhist, 0, 3 * 1024, stream);   // binhist + stats1 + stats2
    histA_kernel<<<NBLK + 160, 256, 0, stream>>>(eix, hist2dT, binhist,
                                                 W1, W2, W3, wt1, wt2, wt3, E, NB, per_block);
    colscan_kernel<<<NB, 256, 0, stream>>>(hist2dT, binhist, binrp, NB);
    passB_kernel<<<NBLK, 256, 0, stream>>>(eix, hist2dT, ibuf, E, NB, per_block);
    binsort2_kernel<<<NB, 256, 0, stream>>>(ibuf, binrp, rp, dis, ep, N);

    // ---- layer 1 ----
    mfma_gemm_kernel<128, false, float><<<gemm_grid, 256, 0, stream>>>(
        x, wt1, nullptr, nullptr, nullptr, 0.f, A, N);
    agg_kernel<128, true, true><<<agg128_grid, 256, 0, stream>>>(
        A, rp, ep, dis, b1, B, partial1, N);
    red_kernel<<<32, 256, 0, stream>>>(partial1, stats1, agg128_grid);

    // ---- layer 2 (BN finalize fused into gemm) ----
    mfma_gemm_kernel<128, true, __hip_bfloat16><<<gemm_grid, 256, 0, stream>>>(
        B, wt2, stats1, g1, be1, invN, A, N);
    agg_kernel<128, true, true><<<agg128_grid, 256, 0, stream>>>(
        A, rp, ep, dis, b2, B, partial2, N);
    red_kernel<<<32, 256, 0, stream>>>(partial2, stats2, agg128_grid);

    // ---- layer 3 ----
    mfma_gemm_kernel<64, true, __hip_bfloat16><<<gemm_grid, 256, 0, stream>>>(
        B, wt3, stats2, g2, be2, invN, A, N);
    agg_kernel<64, false, false><<<agg64_grid, 256, 0, stream>>>(
        A, rp, ep, dis, b3, outp, nullptr, N);
}

// Round 13
// 359.504 us; speedup vs baseline: 1.0343x; 1.0019x over previous
//
#include <hip/hip_runtime.h>
#include <hip/hip_bf16.h>

#define BN_EPS 1e-5f
#define BINSH 9
#define MAXNB 200
#define NBLK 256
#define BIN_CAP 8960

typedef __attribute__((ext_vector_type(8))) short bf16x8v;
typedef __attribute__((ext_vector_type(4))) float f32x4v;

__device__ __forceinline__ float u2f(unsigned x) { return __uint_as_float(x); }
__device__ __forceinline__ unsigned short f2bf(float f) {
    union { __hip_bfloat16 h; unsigned short u; } cv;
    cv.h = __float2bfloat16(f);
    return cv.u;
}

__device__ __forceinline__ int edge_at(const void* p, long long i, int is64) {
    return is64 ? (int)((const long long*)p)[i] : ((const int*)p)[i];
}

__device__ __forceinline__ void detect_is64(const void* eidx, int* sflag, int t) {
    if (t == 0) {
        const int* e32 = (const int*)eidx;
        int nz = 0;
        for (int i = 0; i < 64; ++i) nz += (e32[2 * i + 1] != 0);
        *sflag = (nz == 0) ? 1 : 0;
    }
}

// ---------------- fragment loaders ----------------
__device__ __forceinline__ void load8(const float* p, float* f) {
    float4 v0 = ((const float4*)p)[0];
    float4 v1 = ((const float4*)p)[1];
    f[0] = v0.x; f[1] = v0.y; f[2] = v0.z; f[3] = v0.w;
    f[4] = v1.x; f[5] = v1.y; f[6] = v1.z; f[7] = v1.w;
}
__device__ __forceinline__ void load8(const __hip_bfloat16* p, float* f) {
    uint4 v = *(const uint4*)p;
    f[0] = u2f(v.x << 16); f[1] = u2f(v.x & 0xffff0000u);
    f[2] = u2f(v.y << 16); f[3] = u2f(v.y & 0xffff0000u);
    f[4] = u2f(v.z << 16); f[5] = u2f(v.z & 0xffff0000u);
    f[6] = u2f(v.w << 16); f[7] = u2f(v.w & 0xffff0000u);
}

// ---------------- GEMM body: 256 rows per bx; Wt from bf16-transposed or raw f32 ----------------
template <int DOUT, bool BN, bool RAWW, typename TH>
__device__ __forceinline__ void gemm_body(int bx, const TH* __restrict__ H,
                                          const void* __restrict__ Wsrc,
                                          const float* __restrict__ stats,
                                          const float* __restrict__ g,
                                          const float* __restrict__ be,
                                          float invN,
                                          __hip_bfloat16* __restrict__ out, int N,
                                          char* smem) {
    constexpr int NCT = DOUT / 16;
    constexpr int LDW = 136;
    __hip_bfloat16* sWt = (__hip_bfloat16*)smem;
    float* sBN = (float*)(smem + (size_t)DOUT * LDW * 2);
    const int t = threadIdx.x;
    if (RAWW) {
        const float* W = (const float*)Wsrc;   // f32 [128][DOUT] row-major
        for (int i = t; i < 128 * DOUT; i += 256) {
            int k = i / DOUT, c = i % DOUT;
            sWt[c * LDW + k] = __float2bfloat16(W[i]);
        }
    } else {
        const __hip_bfloat16* Wt = (const __hip_bfloat16*)Wsrc;  // bf16 [DOUT][128]
        for (int i = t; i < DOUT * 16; i += 256) {
            int row = i >> 4, seg = i & 15;
            *(uint4*)&sWt[row * LDW + seg * 8] = ((const uint4*)Wt)[i];
        }
    }
    if (BN && t < 128) {
        float mu  = stats[t] * invN;
        float var = stats[128 + t] * invN - mu * mu;
        float sc  = g[t] * rsqrtf(var + BN_EPS);
        sBN[t]       = sc;
        sBN[128 + t] = be[t] - mu * sc;
    }
    __syncthreads();
    const int lane = t & 63, wid = t >> 6;
    const int kq = lane >> 4, mrow = lane & 15;
#pragma unroll
    for (int gq = 0; gq < 4; ++gq) {
        const int rbase = bx * 256 + wid * 64 + gq * 16;
        if (rbase >= N) break;
        const int lrow = min(rbase + mrow, N - 1);
        bf16x8v afrag[4];
#pragma unroll
        for (int ks = 0; ks < 4; ++ks) {
            const int k0 = ks * 32 + kq * 8;
            float f[8];
            load8(H + (size_t)lrow * 128 + k0, f);
            if (BN) {
                float4 s0 = *(const float4*)&sBN[k0];
                float4 s1 = *(const float4*)&sBN[k0 + 4];
                float4 h0 = *(const float4*)&sBN[128 + k0];
                float4 h1 = *(const float4*)&sBN[128 + k0 + 4];
                f[0] = fmaxf(fmaf(f[0], s0.x, h0.x), 0.f);
                f[1] = fmaxf(fmaf(f[1], s0.y, h0.y), 0.f);
                f[2] = fmaxf(fmaf(f[2], s0.z, h0.z), 0.f);
                f[3] = fmaxf(fmaf(f[3], s0.w, h0.w), 0.f);
                f[4] = fmaxf(fmaf(f[4], s1.x, h1.x), 0.f);
                f[5] = fmaxf(fmaf(f[5], s1.y, h1.y), 0.f);
                f[6] = fmaxf(fmaf(f[6], s1.z, h1.z), 0.f);
                f[7] = fmaxf(fmaf(f[7], s1.w, h1.w), 0.f);
            }
            bf16x8v a;
#pragma unroll
            for (int j = 0; j < 8; ++j) a[j] = (short)f2bf(f[j]);
            afrag[ks] = a;
        }
        f32x4v acc[NCT];
#pragma unroll
        for (int ct = 0; ct < NCT; ++ct) acc[ct] = (f32x4v){0.f, 0.f, 0.f, 0.f};
#pragma unroll
        for (int ct = 0; ct < NCT; ++ct) {
#pragma unroll
            for (int ks = 0; ks < 4; ++ks) {
                bf16x8v bb = *(const bf16x8v*)&sWt[(ct * 16 + mrow) * LDW + ks * 32 + kq * 8];
                acc[ct] = __builtin_amdgcn_mfma_f32_16x16x32_bf16(afrag[ks], bb, acc[ct], 0, 0, 0);
            }
        }
#pragma unroll
        for (int r = 0; r < 4; ++r) {
            int orow = rbase + kq * 4 + r;
            if (orow < N) {
                __hip_bfloat16* op = out + (size_t)orow * DOUT + mrow;
#pragma unroll
                for (int ct = 0; ct < NCT; ++ct) {
                    union { unsigned short u; __hip_bfloat16 h; } cv;
                    cv.u = f2bf(acc[ct][r]);
                    op[ct * 16] = cv.h;
                }
            }
        }
    }
}

// ---------------- mega-fused dispatch #1: histA ∥ wt2/wt3 prep ∥ gemm1 ----------------
__global__ __launch_bounds__(256) void fused_pre_kernel(const void* __restrict__ eidx,
                                                        int* __restrict__ hist2dT,
                                                        int* __restrict__ binhist,
                                                        const float* __restrict__ W2,
                                                        const float* __restrict__ W3,
                                                        __hip_bfloat16* __restrict__ wt2,
                                                        __hip_bfloat16* __restrict__ wt3,
                                                        const float* __restrict__ x,
                                                        const float* __restrict__ W1,
                                                        __hip_bfloat16* __restrict__ A,
                                                        int E, int NB, int per_block, int N) {
    __shared__ __align__(16) char smem[128 * 136 * 2 + 256 * 4];
    const int bx = blockIdx.x;
    const int t = threadIdx.x;
    if (bx < NBLK) {
        // ---- histogram path ----
        int* lh = (int*)smem;
        int* sflag = lh + MAXNB;
        detect_is64(eidx, sflag, t);
        for (int i = t; i < NB; i += 256) lh[i] = 0;
        __syncthreads();
        const int is64 = *sflag;
        long long base = (long long)bx * per_block;
        long long lim  = base + per_block;
        if (lim > E) lim = E;
        for (long long e = base + t; e < lim; e += 256) {
            int d = edge_at(eidx, (long long)E + e, is64);
            atomicAdd(&lh[d >> BINSH], 1);
        }
        __syncthreads();
        for (int i = t; i < NB; i += 256) {
            hist2dT[i * NBLK + bx] = lh[i];
            atomicAdd(&binhist[i], lh[i]);
        }
    } else if (bx < NBLK + 96) {
        // ---- wt2/wt3 transpose (24576 elements) ----
        int i = (bx - NBLK) * 256 + t;
        if (i < 16384) {
            int k = i >> 7, c = i & 127;
            wt2[c * 128 + k] = __float2bfloat16(W2[i]);
        } else if (i < 24576) {
            int j = i - 16384, k = j >> 6, c = j & 63;
            wt3[c * 128 + k] = __float2bfloat16(W3[j]);
        }
    } else {
        // ---- gemm1: A = x @ W1 (raw f32 W, transposed in-block) ----
        gemm_body<128, false, true, float>(bx - NBLK - 96, x, W1,
                                           nullptr, nullptr, nullptr, 0.f, A, N, smem);
    }
}

// ---------------- standalone GEMM (layers 2,3) ----------------
template <int DOUT, bool BN, typename TH>
__global__ __launch_bounds__(256) void mfma_gemm_kernel(const TH* __restrict__ H,
                                                        const __hip_bfloat16* __restrict__ Wt,
                                                        const float* __restrict__ stats,
                                                        const float* __restrict__ g,
                                                        const float* __restrict__ be,
                                                        float invN,
                                                        __hip_bfloat16* __restrict__ out, int N) {
    __shared__ __align__(16) char smem[(size_t)DOUT * 136 * 2 + 256 * 4];
    gemm_body<DOUT, BN, false, TH>(blockIdx.x, H, Wt, stats, g, be, invN, out, N, smem);
}

// ---------------- colscan: per-bin base + column prefix ----------------
__global__ __launch_bounds__(256) void colscan_kernel(int* __restrict__ hist2dT,
                                                      const int* __restrict__ binhist,
                                                      int* __restrict__ binrp, int NB) {
    __shared__ int s[256];
    __shared__ int sbase;
    const int b = blockIdx.x;
    const int t = threadIdx.x;
    s[t] = (t < b) ? binhist[t] : 0;
    __syncthreads();
    for (int off = 128; off > 0; off >>= 1) {
        if (t < off) s[t] += s[t + off];
        __syncthreads();
    }
    if (t == 0) sbase = s[0];
    __syncthreads();
    const int base = sbase;
    if (t == 0) {
        binrp[b] = base;
        if (b == NB - 1) binrp[NB] = base + binhist[b];
    }
    int v = hist2dT[b * NBLK + t];
    s[t] = v;
    __syncthreads();
    for (int off = 1; off < 256; off <<= 1) {
        int x = (t >= off) ? s[t - off] : 0;
        __syncthreads();
        s[t] += x;
        __syncthreads();
    }
    hist2dT[b * NBLK + t] = base + s[t] - v;
}

// ---------------- pass B: scatter packed (src | dl<<17) into reserved ranges ----------------
__global__ __launch_bounds__(256) void passB_kernel(const void* __restrict__ eidx,
                                                    const int* __restrict__ hist2dT,
                                                    int* __restrict__ ibuf,
                                                    int E, int NB, int per_block) {
    __shared__ int lbase[MAXNB];
    __shared__ int lcur[MAXNB];
    __shared__ int sflag;
    const int t = threadIdx.x;
    detect_is64(eidx, &sflag, t);
    for (int i = t; i < NB; i += 256) {
        lbase[i] = hist2dT[i * NBLK + blockIdx.x];
        lcur[i]  = 0;
    }
    __syncthreads();
    const int is64 = sflag;
    long long base = (long long)blockIdx.x * per_block;
    long long lim  = base + per_block;
    if (lim > E) lim = E;
    for (long long e = base + t; e < lim; e += 256) {
        int sN = edge_at(eidx, e, is64);
        int d  = edge_at(eidx, (long long)E + e, is64);
        int b  = d >> BINSH;
        int dl = d & ((1 << BINSH) - 1);
        int pos = lbase[b] + atomicAdd(&lcur[b], 1);
        ibuf[pos] = sN | (dl << 17);
    }
}

// ---------------- per-bin exact sort (coalesced-write); computes rp + dis ----------------
__global__ __launch_bounds__(256) void binsort2_kernel(const int* __restrict__ ibuf,
                                                       const int* __restrict__ binrp,
                                                       int* __restrict__ rp,
                                                       float* __restrict__ dis,
                                                       int* __restrict__ ep, int N) {
    const int b  = blockIdx.x;
    const int d0 = b << BINSH;
    const int dc = min(1 << BINSH, N - d0);
    __shared__ int lcnt[1 << BINSH];
    __shared__ int lofs[1 << BINSH];
    __shared__ int s2[256];
    __shared__ unsigned short sperm[BIN_CAP];
    const int t = threadIdx.x;
    lcnt[t] = 0; lcnt[t + 256] = 0;
    __syncthreads();
    const int ib0 = binrp[b], ib1 = binrp[b + 1];
    const int nE  = ib1 - ib0;
    for (int i = t; i < nE; i += 256) {
        atomicAdd(&lcnt[ibuf[ib0 + i] >> 17], 1);
    }
    __syncthreads();
    const int c0 = lcnt[2 * t], c1 = lcnt[2 * t + 1];
    const int pair = c0 + c1;
    s2[t] = pair;
    __syncthreads();
    for (int off = 1; off < 256; off <<= 1) {
        int x = (t >= off) ? s2[t - off] : 0;
        __syncthreads();
        s2[t] += x;
        __syncthreads();
    }
    const int pexcl = s2[t] - pair;
    if (2 * t < dc) {
        rp[d0 + 2 * t + 1] = ib0 + pexcl + c0;
        dis[d0 + 2 * t]    = rsqrtf((float)c0 + 1.0f);
    }
    if (2 * t + 1 < dc) {
        rp[d0 + 2 * t + 2] = ib0 + pexcl + pair;
        dis[d0 + 2 * t + 1] = rsqrtf((float)c1 + 1.0f);
    }
    if (b == 0 && t == 0) rp[0] = 0;
    lofs[2 * t]     = pexcl;
    lofs[2 * t + 1] = pexcl + c0;
    __syncthreads();
    if (nE <= BIN_CAP) {
        for (int i = t; i < nE; i += 256) {
            int pos = atomicAdd(&lofs[ibuf[ib0 + i] >> 17], 1);
            sperm[pos] = (unsigned short)i;
        }
        __syncthreads();
        for (int j = t; j < nE; j += 256)
            ep[ib0 + j] = ibuf[ib0 + (int)sperm[j]] & 0x1FFFF;
    } else {
        for (int i = t; i < nE; i += 256) {
            int v = ibuf[ib0 + i];
            int pos = ib0 + atomicAdd(&lofs[v >> 17], 1);
            ep[pos] = v & 0x1FFFF;
        }
    }
}

// ---------------- aggregation: 8 cols/thread, factored weights, optional BN partials ----------------
__device__ __forceinline__ void acc8(float* a, uint4 v, float w) {
    a[0] += u2f(v.x << 16) * w;  a[1] += u2f(v.x & 0xffff0000u) * w;
    a[2] += u2f(v.y << 16) * w;  a[3] += u2f(v.y & 0xffff0000u) * w;
    a[4] += u2f(v.z << 16) * w;  a[5] += u2f(v.z & 0xffff0000u) * w;
    a[6] += u2f(v.w << 16) * w;  a[7] += u2f(v.w & 0xffff0000u) * w;
}

template <int D, bool OUTBF, bool STATS>
__global__ __launch_bounds__(256) void agg_kernel(const __hip_bfloat16* __restrict__ hw,
                                                  const int* __restrict__ rp,
                                                  const int* __restrict__ ep,
                                                  const float* __restrict__ dis,
                                                  const float* __restrict__ bias,
                                                  void* __restrict__ outv,
                                                  float* __restrict__ partial, int N) {
    constexpr int LPR = D / 8;
    const int t = threadIdx.x;
    const int gtid = blockIdx.x * 256 + t;
    const int idx  = gtid / LPR;
    const int lane = gtid % LPR;
    const bool valid = idx < N;
    if (!STATS && !valid) return;
    const int n = valid ? idx : (N - 1);
    const uint4* hw8 = (const uint4*)hw;
    float a[8] = {0.f, 0.f, 0.f, 0.f, 0.f, 0.f, 0.f, 0.f};
    const float dn = dis[n];
    uint4 hv = hw8[(size_t)n * LPR + lane];
    acc8(a, hv, dn);
    int e0 = rp[n], e1 = rp[n + 1];
    int e = e0;
    for (; e + 4 <= e1; e += 4) {
        int p0 = ep[e + 0];
        int p1 = ep[e + 1];
        int p2 = ep[e + 2];
        int p3 = ep[e + 3];
        uint4 v0 = hw8[(size_t)p0 * LPR + lane];
        uint4 v1 = hw8[(size_t)p1 * LPR + lane];
        uint4 v2 = hw8[(size_t)p2 * LPR + lane];
        uint4 v3 = hw8[(size_t)p3 * LPR + lane];
        acc8(a, v0, dis[p0]);
        acc8(a, v1, dis[p1]);
        acc8(a, v2, dis[p2]);
        acc8(a, v3, dis[p3]);
    }
    for (; e < e1; ++e) {
        int p = ep[e];
        uint4 v = hw8[(size_t)p * LPR + lane];
        acc8(a, v, dis[p]);
    }
    float4 b0 = *(const float4*)(bias + lane * 8);
    float4 b1 = *(const float4*)(bias + lane * 8 + 4);
    a[0] = fmaf(a[0], dn, b0.x); a[1] = fmaf(a[1], dn, b0.y);
    a[2] = fmaf(a[2], dn, b0.z); a[3] = fmaf(a[3], dn, b0.w);
    a[4] = fmaf(a[4], dn, b1.x); a[5] = fmaf(a[5], dn, b1.y);
    a[6] = fmaf(a[6], dn, b1.z); a[7] = fmaf(a[7], dn, b1.w);
    if (STATS) {
        __shared__ float ls[16][128];
        const int r16 = t >> 4;
#pragma unroll
        for (int j = 0; j < 8; ++j) ls[r16][lane * 8 + j] = valid ? a[j] : 0.f;
        __syncthreads();
        if (t < 128) {
            float s = 0.f, q = 0.f;
#pragma unroll
            for (int r = 0; r < 16; ++r) {
                float v = ls[r][t];
                s += v;
                q += v * v;
            }
            partial[(size_t)blockIdx.x * 256 + t]       = s;
            partial[(size_t)blockIdx.x * 256 + 128 + t] = q;
        }
    }
    if (valid) {
        if (OUTBF) {
            uint4 o;
            o.x = (unsigned)f2bf(a[0]) | ((unsigned)f2bf(a[1]) << 16);
            o.y = (unsigned)f2bf(a[2]) | ((unsigned)f2bf(a[3]) << 16);
            o.z = (unsigned)f2bf(a[4]) | ((unsigned)f2bf(a[5]) << 16);
            o.w = (unsigned)f2bf(a[6]) | ((unsigned)f2bf(a[7]) << 16);
            ((uint4*)outv)[(size_t)n * LPR + lane] = o;
        } else {
            float4* op = (float4*)outv + ((size_t)n * D + lane * 8) / 4;
            op[0] = make_float4(a[0], a[1], a[2], a[3]);
            op[1] = make_float4(a[4], a[5], a[6], a[7]);
        }
    }
}

// ---------------- partial reduction -> stats ----------------
__global__ __launch_bounds__(256) void red_kernel(const float* __restrict__ partial,
                                                  float* __restrict__ stats, int nb) {
    const int t = threadIdx.x;
    const int per = (nb + gridDim.x - 1) / gridDim.x;
    const int r0 = blockIdx.x * per;
    const int r1 = min(r0 + per, nb);
    float s = 0.f;
    for (int r = r0; r < r1; ++r) s += partial[(size_t)r * 256 + t];
    atomicAdd(&stats[t], s);
}

// ---------------- host launch ----------------
extern "C" void kernel_launch(void* const* d_in, const int* in_sizes, int n_in,
                              void* d_out, int out_size, void* d_ws, size_t ws_size,
                              hipStream_t stream) {
    const float* x   = (const float*)d_in[0];
    const void*  eix = d_in[1];
    const float* W1  = (const float*)d_in[2];
    const float* b1  = (const float*)d_in[3];
    const float* g1  = (const float*)d_in[4];
    const float* be1 = (const float*)d_in[5];
    const float* W2  = (const float*)d_in[6];
    const float* b2  = (const float*)d_in[7];
    const float* g2  = (const float*)d_in[8];
    const float* be2 = (const float*)d_in[9];
    const float* W3  = (const float*)d_in[10];
    const float* b3  = (const float*)d_in[11];
    float* outp = (float*)d_out;

    const int N = in_sizes[0] / 128;
    const int E = in_sizes[1] / 2;
    const int NB = (N + (1 << BINSH) - 1) >> BINSH;

    char* base = (char*)d_ws;
    size_t off = 0;
    auto alloc = [&](size_t bytes) -> char* {
        char* p = base + off;
        off = (off + bytes + 255) & ~(size_t)255;
        return p;
    };
    __hip_bfloat16* A = (__hip_bfloat16*)alloc((size_t)N * 128 * 2);
    __hip_bfloat16* B = (__hip_bfloat16*)alloc((size_t)N * 128 * 2);
    int*   rp      = (int*)alloc((size_t)(N + 1) * 4);
    float* dis     = (float*)alloc((size_t)N * 4);
    int*   ep      = (int*)alloc((size_t)E * 4);
    int*   ibuf    = (int*)alloc((size_t)E * 4);    // packed; dead after binsort2 -> partial1
    int*   hist2dT = (int*)alloc((size_t)MAXNB * NBLK * 4);
    int*   binrp   = (int*)alloc((MAXNB + 1) * 4);
    int*   binhist = (int*)alloc(MAXNB * 4);
    float* stats1  = (float*)alloc(256 * 4);
    float* stats2  = (float*)alloc(256 * 4);
    __hip_bfloat16* wt2 = (__hip_bfloat16*)alloc(128 * 128 * 2);
    __hip_bfloat16* wt3 = (__hip_bfloat16*)alloc(64 * 128 * 2);
    const int agg128_grid = (int)(((long long)N * 16 + 255) / 256);
    float* partial2 = (float*)alloc((size_t)agg128_grid * 256 * 4);
    (void)ws_size; (void)n_in; (void)out_size;

    const int per_block   = (E + NBLK - 1) / NBLK;
    const int gemm_grid   = (N + 255) / 256;
    const int agg64_grid  = (int)(((long long)N * 8 + 255) / 256);
    const float invN = 1.0f / (float)N;
    float* partial1 = (float*)ibuf;                 // agg128_grid*256*4 == E*4

    // ---- dispatch 1: memset; dispatch 2: histA ∥ wt-prep ∥ gemm1 ----
    hipMemsetAsync(binhist, 0, 3 * 1024, stream);   // binhist + stats1 + stats2
    fused_pre_kernel<<<NBLK + 96 + gemm_grid, 256, 0, stream>>>(
        eix, hist2dT, binhist, W2, W3, wt2, wt3, x, W1, A, E, NB, per_block, N);
    colscan_kernel<<<NB, 256, 0, stream>>>(hist2dT, binhist, binrp, NB);
    passB_kernel<<<NBLK, 256, 0, stream>>>(eix, hist2dT, ibuf, E, NB, per_block);
    binsort2_kernel<<<NB, 256, 0, stream>>>(ibuf, binrp, rp, dis, ep, N);

    // ---- layer 1 agg (+BN partials; partial1 overwrites dead ibuf) ----
    agg_kernel<128, true, true><<<agg128_grid, 256, 0, stream>>>(
        A, rp, ep, dis, b1, B, partial1, N);
    red_kernel<<<32, 256, 0, stream>>>(partial1, stats1, agg128_grid);

    // ---- layer 2 ----
    mfma_gemm_kernel<128, true, __hip_bfloat16><<<gemm_grid, 256, 0, stream>>>(
        B, wt2, stats1, g1, be1, invN, A, N);
    agg_kernel<128, true, true><<<agg128_grid, 256, 0, stream>>>(
        A, rp, ep, dis, b2, B, partial2, N);
    red_kernel<<<32, 256, 0, stream>>>(partial2, stats2, agg128_grid);

    // ---- layer 3 ----
    mfma_gemm_kernel<64, true, __hip_bfloat16><<<gemm_grid, 256, 0, stream>>>(
        B, wt3, stats2, g2, be2, invN, A, N);
    agg_kernel<64, false, false><<<agg64_grid, 256, 0, stream>>>(
        A, rp, ep, dis, b3, outp, nullptr, N);
}